// Round 1
// 816.299 us; speedup vs baseline: 1.0990x; 1.0990x over previous
//
#include <hip/hip_runtime.h>
#include <hip/hip_bf16.h>
#include <stdint.h>

#define DEVI __device__ __forceinline__

typedef __attribute__((ext_vector_type(8))) short bf16x8;   // 8 bf16 = 4 VGPRs
typedef __attribute__((ext_vector_type(4))) float f32x4;    // MFMA acc

static constexpr int Bb = 4, Ss = 8192, Ff = 1024, Hh = 16, Dd = 64;
static constexpr int Mm = Bb * Ss;                 // 32768 rows of the projection GEMMs
static constexpr int Kk = Ff;                      // 1024
static constexpr int PROJ_ELEMS = Mm * Ff;         // 33554432 per projection

// ---------- small helpers ----------
DEVI ushort f2bf(float f) {            // fp32 -> bf16 RNE (manual, finite inputs)
  uint32_t u = __builtin_bit_cast(uint32_t, f);
  u += 0x7fffu + ((u >> 16) & 1u);
  return (ushort)(u >> 16);
}
DEVI float bf2f(ushort u) { return __builtin_bit_cast(float, (uint32_t)u << 16); }

DEVI uint32_t pack2(float a, float b) {  // 2×fp32 -> packed bf16x2 (manual RNE)
  return (uint32_t)f2bf(a) | ((uint32_t)f2bf(b) << 16);
}

DEVI void async16(void* lds, const void* g) {  // 16B/lane global->LDS DMA
  __builtin_amdgcn_global_load_lds((const __attribute__((address_space(1))) void*)g,
                                   (__attribute__((address_space(3))) void*)lds,
                                   16, 0, 0);
}

// ---------- kernel 1: W (K,N) fp32 -> Wt (N,K) bf16, so GEMM B-frags are K-contiguous ----------
__global__ __launch_bounds__(256) void wt_kernel(const float* __restrict__ Wq,
                                                 const float* __restrict__ Wk,
                                                 const float* __restrict__ Wv,
                                                 ushort* __restrict__ wt) {
  __shared__ float tile[64][65];
  int b = blockIdx.x;
  const int w = b >> 8; b &= 255;
  const int kt = b >> 4, nt = b & 15;         // 16x16 tiles of 64x64
  const float* Wsrc = (w == 0) ? Wq : ((w == 1) ? Wk : Wv);
  ushort* dst = wt + (size_t)w * 1024 * 1024;
  const int t = threadIdx.x;
  const int r = t >> 6, c = t & 63;
#pragma unroll
  for (int i = 0; i < 16; i++) {
    const int kk = kt * 64 + r + i * 4;
    tile[r + i * 4][c] = Wsrc[(size_t)kk * 1024 + nt * 64 + c];
  }
  __syncthreads();
#pragma unroll
  for (int i = 0; i < 16; i++) {
    const int nn = nt * 64 + r + i * 4;
    dst[(size_t)nn * 1024 + kt * 64 + c] = f2bf(tile[c][r + i * 4]);
  }
}

// ---------- kernel 2: QKV projection GEMM + fused per-head LayerNorm on K,V ----------
// C[proj] (32768x1024 bf16) = A[proj] (fp32, row-major MxK) * W (via Wt, NxK bf16)
// 128x128 tile, BK=64, 4 waves in 2x2, 16x16x32 bf16 MFMA, B via global_load_lds(16B).
// XCD swizzle: physical bx -> logical l so the 8 N-tiles sharing an A strip land on
// ONE XCD's L2 (default round-robin put them on 8 different, non-coherent L2s).
// LN fusion: a wave's 4 j-frags x 16 lanes span exactly one aligned 64-col head group;
// h = (m0>>9)&15 is tile-uniform (128-row tiles never cross a 512-row boundary).
__global__ __launch_bounds__(256, 3) void gemm_qkv_kernel(
    const float* __restrict__ Aq, const float* __restrict__ Ak,
    const float* __restrict__ Av, const ushort* __restrict__ Wt,
    ushort* __restrict__ Cout,
    const float* __restrict__ ksc, const float* __restrict__ kbi,
    const float* __restrict__ vsc, const float* __restrict__ vbi) {
  __shared__ __align__(16) ushort As[128][64];
  __shared__ __align__(16) ushort Bs[128][64];

  const int bx0 = blockIdx.x;
  // bijective XCD swizzle (6144 = 8 * 768): siblings l=8m..8m+7 share bx0&7 == XCD
  const int bx = (bx0 & 7) * 768 + (bx0 >> 3);
  const int proj = bx >> 11;
  const int t2 = bx & 2047;
  const int mt = t2 >> 3;       // 256 M-tiles
  const int nt = t2 & 7;        // 8 N-tiles (fastest -> same A strip in 8 logical siblings)
  const float* A = (proj == 0) ? Aq : ((proj == 1) ? Ak : Av);
  const ushort* Bw = Wt + (size_t)proj * 1024 * 1024;
  ushort* C = Cout + (size_t)proj * PROJ_ELEMS;
  const int m0 = mt * 128, n0 = nt * 128;
  const int tid = threadIdx.x;
  const int lane = tid & 63;
  const int wave = tid >> 6;
  const int wy = wave >> 1, wx = wave & 1;

  // A staging map: thread -> (row = tid>>3 + i*32, col = (tid&7)*8); LDS writes contiguous per wave
  const int ar = tid >> 3;
  const int ac = (tid & 7) * 8;
  const float* Abase = A + (size_t)m0 * Kk;

  const f32x4 fzero = {0.0f, 0.0f, 0.0f, 0.0f};
  f32x4 acc[4][4];
#pragma unroll
  for (int i = 0; i < 4; i++)
#pragma unroll
    for (int j = 0; j < 4; j++) acc[i][j] = fzero;

  for (int k0 = 0; k0 < Kk; k0 += 64) {
    // B: async DMA, 4 segs/wave, each seg = 8 rows x 64 cols bf16 = 1KB (lane l -> base + 16*l)
#pragma unroll
    for (int j = 0; j < 4; j++) {
      const int seg = wave * 4 + j;
      const int brow = seg * 8 + (lane >> 3);
      const int bcol = (lane & 7) * 8;
      async16(&Bs[seg * 8][0], Bw + (size_t)(n0 + brow) * Kk + k0 + bcol);
    }
    // A: fp32 loads + packed cvt + ds_write_b128
#pragma unroll
    for (int i = 0; i < 4; i++) {
      const int row = ar + i * 32;
      const float* src = Abase + (size_t)row * Kk + k0 + ac;
      const float4 f0 = *(const float4*)src;
      const float4 f1 = *(const float4*)(src + 4);
      uint4 v;
      v.x = pack2(f0.x, f0.y);
      v.y = pack2(f0.z, f0.w);
      v.z = pack2(f1.x, f1.y);
      v.w = pack2(f1.z, f1.w);
      *(uint4*)&As[row][ac] = v;
    }
    __syncthreads();
#pragma unroll
    for (int ks = 0; ks < 2; ks++) {
      bf16x8 af[4], bv[4];
#pragma unroll
      for (int i = 0; i < 4; i++)
        af[i] = *(const bf16x8*)&As[wy * 64 + i * 16 + (lane & 15)][ks * 32 + (lane >> 4) * 8];
#pragma unroll
      for (int j = 0; j < 4; j++)
        bv[j] = *(const bf16x8*)&Bs[wx * 64 + j * 16 + (lane & 15)][ks * 32 + (lane >> 4) * 8];
#pragma unroll
      for (int i = 0; i < 4; i++)
#pragma unroll
        for (int j = 0; j < 4; j++)
          acc[i][j] = __builtin_amdgcn_mfma_f32_16x16x32_bf16(af[i], bv[j], acc[i][j], 0, 0, 0);
    }
    __syncthreads();
  }

  // epilogue: C/D layout col=lane&15, row=(lane>>4)*4+reg
  if (proj == 0) {
#pragma unroll
    for (int i = 0; i < 4; i++) {
      const int rbase = m0 + wy * 64 + i * 16 + (lane >> 4) * 4;
#pragma unroll
      for (int j = 0; j < 4; j++) {
        const int col = n0 + wx * 64 + j * 16 + (lane & 15);
#pragma unroll
        for (int r = 0; r < 4; r++)
          C[(size_t)(rbase + r) * 1024 + col] = f2bf(acc[i][j][r]);
      }
    }
  } else {
    // fused per-head LayerNorm on the fp32 accumulators (K: proj==1, V: proj==2)
    const float* sc = (proj == 1) ? ksc : vsc;
    const float* bi = (proj == 1) ? kbi : vbi;
    const int h = (m0 >> 9) & 15;     // tile-uniform head index
    float scv[4], biv[4];
#pragma unroll
    for (int j = 0; j < 4; j++) {
      const int d = j * 16 + (lane & 15);      // = col & 63 (group aligned to 64)
      scv[j] = sc[h * 64 + d];
      biv[j] = bi[h * 64 + d];
    }
#pragma unroll
    for (int i = 0; i < 4; i++) {
      const int rbase = m0 + wy * 64 + i * 16 + (lane >> 4) * 4;
#pragma unroll
      for (int r = 0; r < 4; r++) {
        // one output row's 64-wide head group = 4 j-regs x 16 lanes of this subgroup
        float s = 0.f, sq = 0.f;
#pragma unroll
        for (int j = 0; j < 4; j++) {
          const float x = acc[i][j][r];
          s += x;
          sq += x * x;
        }
        s += __shfl_xor(s, 1); s += __shfl_xor(s, 2);
        s += __shfl_xor(s, 4); s += __shfl_xor(s, 8);
        sq += __shfl_xor(sq, 1); sq += __shfl_xor(sq, 2);
        sq += __shfl_xor(sq, 4); sq += __shfl_xor(sq, 8);
        const float mean = s * (1.0f / 64.0f);
        const float var = sq * (1.0f / 64.0f) - mean * mean;
        const float rs = rsqrtf(var + 1e-6f);
#pragma unroll
        for (int j = 0; j < 4; j++) {
          const int col = n0 + wx * 64 + j * 16 + (lane & 15);
          C[(size_t)(rbase + r) * 1024 + col] =
              f2bf((acc[i][j][r] - mean) * rs * scv[j] + biv[j]);
        }
      }
    }
  }
}

// ---------- kernel 3: p_raw += K^T V partials (split-K over 32 chunks of 256 rows) ----------
__global__ __launch_bounds__(256) void pattn_kernel(const ushort* __restrict__ kp,
                                                    const ushort* __restrict__ vp,
                                                    float* __restrict__ praw) {
  __shared__ __align__(16) ushort kT[64][72];   // (d, n) transposed, pad 72 breaks bank stride
  __shared__ __align__(16) ushort vT[64][72];   // (e, n)
  const int bh = blockIdx.x >> 5;
  const int nc = blockIdx.x & 31;
  const ushort* kb = kp + ((size_t)bh << 19) + (size_t)nc * 16384;
  const ushort* vb = vp + ((size_t)bh << 19) + (size_t)nc * 16384;
  const int tid = threadIdx.x;
  const int lane = tid & 63;
  const int wave = tid >> 6;
  const int d0 = wave * 16;
  const f32x4 fzero = {0.0f, 0.0f, 0.0f, 0.0f};
  f32x4 acc[4];
#pragma unroll
  for (int e = 0; e < 4; e++) acc[e] = fzero;

  for (int c = 0; c < 4; c++) {   // 4 sub-chunks of 64 n-rows
    const ushort* kc = kb + c * 4096;
    const ushort* vc = vb + c * 4096;
    // lane = n index; wave covers d0..d0+15
    const uint4 ka = *(const uint4*)(kc + (size_t)lane * 64 + d0);
    const uint4 ka2 = *(const uint4*)(kc + (size_t)lane * 64 + d0 + 8);
    const uint4 va = *(const uint4*)(vc + (size_t)lane * 64 + d0);
    const uint4 va2 = *(const uint4*)(vc + (size_t)lane * 64 + d0 + 8);
    __syncthreads();   // previous compute done before overwriting LDS
    const uint32_t* kw = (const uint32_t*)&ka;
    const uint32_t* kw2 = (const uint32_t*)&ka2;
    const uint32_t* vw = (const uint32_t*)&va;
    const uint32_t* vw2 = (const uint32_t*)&va2;
#pragma unroll
    for (int j = 0; j < 4; j++) {   // all lanes same d -> contiguous 2B writes, conflict-free
      kT[d0 + 2 * j][lane] = (ushort)(kw[j] & 0xffffu);
      kT[d0 + 2 * j + 1][lane] = (ushort)(kw[j] >> 16);
      kT[d0 + 8 + 2 * j][lane] = (ushort)(kw2[j] & 0xffffu);
      kT[d0 + 8 + 2 * j + 1][lane] = (ushort)(kw2[j] >> 16);
      vT[d0 + 2 * j][lane] = (ushort)(vw[j] & 0xffffu);
      vT[d0 + 2 * j + 1][lane] = (ushort)(vw[j] >> 16);
      vT[d0 + 8 + 2 * j][lane] = (ushort)(vw2[j] & 0xffffu);
      vT[d0 + 8 + 2 * j + 1][lane] = (ushort)(vw2[j] >> 16);
    }
    __syncthreads();
#pragma unroll
    for (int ks = 0; ks < 2; ks++) {
      const bf16x8 af = *(const bf16x8*)&kT[wave * 16 + (lane & 15)][ks * 32 + (lane >> 4) * 8];
#pragma unroll
      for (int e = 0; e < 4; e++) {
        const bf16x8 bv = *(const bf16x8*)&vT[e * 16 + (lane & 15)][ks * 32 + (lane >> 4) * 8];
        acc[e] = __builtin_amdgcn_mfma_f32_16x16x32_bf16(af, bv, acc[e], 0, 0, 0);
      }
    }
  }
#pragma unroll
  for (int e = 0; e < 4; e++)
#pragma unroll
    for (int r = 0; r < 4; r++) {
      const int drow = wave * 16 + (lane >> 4) * 4 + r;
      const int ecol = e * 16 + (lane & 15);
      atomicAdd(&praw[(size_t)bh * 4096 + drow * 64 + ecol], acc[e][r]);
    }
}

// ---------- kernel 4: p_out = p_raw / 8192 ----------
__global__ __launch_bounds__(256) void scalep_kernel(const float* __restrict__ praw,
                                                     float* __restrict__ pout) {
  const int i = blockIdx.x * 256 + threadIdx.x;
  pout[i] = praw[i] * (1.0f / 8192.0f);
}

// ---------- kernel 5: att = Q * (p_raw/8192) per (b,h); A-frags straight from global ----------
__global__ __launch_bounds__(256) void outgemm_kernel(const ushort* __restrict__ qp,
                                                      const float* __restrict__ praw,
                                                      float* __restrict__ xout) {
  __shared__ __align__(16) ushort pT[64][72];   // (e, d) so B-frags are d-contiguous
  const int bh = blockIdx.x >> 4;
  const int mc = blockIdx.x & 15;               // 16 chunks of 512 rows
  const ushort* qb = qp + ((size_t)bh << 19) + (size_t)mc * 512 * 64;
  float* ob = xout + ((size_t)bh << 19) + (size_t)mc * 512 * 64;
  const float* pb = praw + (size_t)bh * 4096;
  const int tid = threadIdx.x;
  const int lane = tid & 63;
  const int wave = tid >> 6;
  for (int i = tid; i < 4096; i += 256) {
    const int d = i >> 6, e = i & 63;
    pT[e][d] = f2bf(pb[i] * (1.0f / 8192.0f));
  }
  __syncthreads();
  bf16x8 bv[4][2];
#pragma unroll
  for (int e = 0; e < 4; e++)
#pragma unroll
    for (int ks = 0; ks < 2; ks++)
      bv[e][ks] = *(const bf16x8*)&pT[e * 16 + (lane & 15)][ks * 32 + (lane >> 4) * 8];
  const f32x4 fzero = {0.0f, 0.0f, 0.0f, 0.0f};
  for (int it = 0; it < 8; it++) {
    const int rbase = it * 64 + wave * 16;
    const ushort* qrow = qb + (size_t)rbase * 64;
    const bf16x8 a0 = *(const bf16x8*)(qrow + (size_t)(lane & 15) * 64 + (lane >> 4) * 8);
    const bf16x8 a1 = *(const bf16x8*)(qrow + (size_t)(lane & 15) * 64 + (lane >> 4) * 8 + 32);
    f32x4 acc[4];
#pragma unroll
    for (int e = 0; e < 4; e++) acc[e] = fzero;
#pragma unroll
    for (int e = 0; e < 4; e++) {
      acc[e] = __builtin_amdgcn_mfma_f32_16x16x32_bf16(a0, bv[e][0], acc[e], 0, 0, 0);
      acc[e] = __builtin_amdgcn_mfma_f32_16x16x32_bf16(a1, bv[e][1], acc[e], 0, 0, 0);
    }
#pragma unroll
    for (int e = 0; e < 4; e++)
#pragma unroll
      for (int r = 0; r < 4; r++)
        ob[(size_t)(rbase + (lane >> 4) * 4 + r) * 64 + e * 16 + (lane & 15)] = acc[e][r];
  }
}

extern "C" void kernel_launch(void* const* d_in, const int* in_sizes, int n_in,
                              void* d_out, int out_size, void* d_ws, size_t ws_size,
                              hipStream_t stream) {
  const float* q_in = (const float*)d_in[0];
  const float* k_in = (const float*)d_in[1];
  const float* v_in = (const float*)d_in[2];
  const float* Wq = (const float*)d_in[3];
  const float* Wk = (const float*)d_in[4];
  const float* Wv = (const float*)d_in[5];
  const float* ksc = (const float*)d_in[6];
  const float* kbi = (const float*)d_in[7];
  const float* vsc = (const float*)d_in[8];
  const float* vbi = (const float*)d_in[9];

  // ws layout: q/k/v projections bf16 (3x64MB) | Wt bf16 (3x2MB) | p_raw fp32 (1MB)
  ushort* q_proj = (ushort*)d_ws;
  ushort* k_proj = q_proj + (size_t)PROJ_ELEMS;
  ushort* v_proj = k_proj + (size_t)PROJ_ELEMS;
  ushort* wtb = v_proj + (size_t)PROJ_ELEMS;
  float* praw = (float*)(wtb + (size_t)3 * 1024 * 1024);

  float* att = (float*)d_out;                    // 33554432 fp32
  float* pout = att + (size_t)PROJ_ELEMS;        // 262144 fp32

  wt_kernel<<<768, 256, 0, stream>>>(Wq, Wk, Wv, wtb);
  gemm_qkv_kernel<<<6144, 256, 0, stream>>>(q_in, k_in, v_in, wtb, q_proj,
                                            ksc, kbi, vsc, vbi);
  (void)hipMemsetAsync(praw, 0, (size_t)Bb * Hh * 64 * 64 * sizeof(float), stream);
  pattn_kernel<<<2048, 256, 0, stream>>>(k_proj, v_proj, praw);
  scalep_kernel<<<1024, 256, 0, stream>>>(praw, pout);
  outgemm_kernel<<<1024, 256, 0, stream>>>(q_proj, praw, att);
}

// Round 2
// 784.683 us; speedup vs baseline: 1.1432x; 1.0403x over previous
//
#include <hip/hip_runtime.h>
#include <hip/hip_bf16.h>
#include <stdint.h>

#define DEVI __device__ __forceinline__

typedef __attribute__((ext_vector_type(8))) short bf16x8;   // 8 bf16 = 4 VGPRs
typedef __attribute__((ext_vector_type(4))) float f32x4;    // MFMA acc

static constexpr int Bb = 4, Ss = 8192, Ff = 1024, Hh = 16, Dd = 64;
static constexpr int Mm = Bb * Ss;                 // 32768 rows of the projection GEMMs
static constexpr int Kk = Ff;                      // 1024
static constexpr int PROJ_ELEMS = Mm * Ff;         // 33554432 per projection

// ---------- small helpers ----------
DEVI ushort f2bf(float f) {            // fp32 -> bf16 RNE (manual, finite inputs)
  uint32_t u = __builtin_bit_cast(uint32_t, f);
  u += 0x7fffu + ((u >> 16) & 1u);
  return (ushort)(u >> 16);
}
DEVI float bf2f(ushort u) { return __builtin_bit_cast(float, (uint32_t)u << 16); }

DEVI uint32_t pack2(float a, float b) {  // 2×fp32 -> packed bf16x2 (manual RNE)
  return (uint32_t)f2bf(a) | ((uint32_t)f2bf(b) << 16);
}

DEVI void async16(void* lds, const void* g) {  // 16B/lane global->LDS DMA
  __builtin_amdgcn_global_load_lds((const __attribute__((address_space(1))) void*)g,
                                   (__attribute__((address_space(3))) void*)lds,
                                   16, 0, 0);
}

// ---------- kernel 0: fp32 -> bf16 streaming cast of q/k/v activations ----------
// Numerically identical to the old in-GEMM cvt (same RNE point). 6144 blocks.
__global__ __launch_bounds__(256) void cast_kernel(const float* __restrict__ q,
                                                   const float* __restrict__ k,
                                                   const float* __restrict__ v,
                                                   ushort* __restrict__ abf) {
  const int b = blockIdx.x;
  const int proj = b >> 11;                      // 2048 blocks per tensor
  const float* src = (proj == 0) ? q : ((proj == 1) ? k : v);
  ushort* dst = abf + (size_t)proj * PROJ_ELEMS;
  const int tid0 = (b & 2047) * 256 + threadIdx.x;   // 524288 threads per tensor
#pragma unroll
  for (int p = 0; p < 8; ++p) {
    const size_t i = ((size_t)p * 524288 + (size_t)tid0) * 8;
    const float4 f0 = *(const float4*)(src + i);
    const float4 f1 = *(const float4*)(src + i + 4);
    uint4 o;
    o.x = pack2(f0.x, f0.y);
    o.y = pack2(f0.z, f0.w);
    o.z = pack2(f1.x, f1.y);
    o.w = pack2(f1.z, f1.w);
    *(uint4*)(dst + i) = o;
  }
}

// ---------- kernel 1: W (K,N) fp32 -> Wt (N,K) bf16, so GEMM B-frags are K-contiguous ----------
__global__ __launch_bounds__(256) void wt_kernel(const float* __restrict__ Wq,
                                                 const float* __restrict__ Wk,
                                                 const float* __restrict__ Wv,
                                                 ushort* __restrict__ wt) {
  __shared__ float tile[64][65];
  int b = blockIdx.x;
  const int w = b >> 8; b &= 255;
  const int kt = b >> 4, nt = b & 15;         // 16x16 tiles of 64x64
  const float* Wsrc = (w == 0) ? Wq : ((w == 1) ? Wk : Wv);
  ushort* dst = wt + (size_t)w * 1024 * 1024;
  const int t = threadIdx.x;
  const int r = t >> 6, c = t & 63;
#pragma unroll
  for (int i = 0; i < 16; i++) {
    const int kk = kt * 64 + r + i * 4;
    tile[r + i * 4][c] = Wsrc[(size_t)kk * 1024 + nt * 64 + c];
  }
  __syncthreads();
#pragma unroll
  for (int i = 0; i < 16; i++) {
    const int nn = nt * 64 + r + i * 4;
    dst[(size_t)nn * 1024 + kt * 64 + c] = f2bf(tile[c][r + i * 4]);
  }
}

// ---------- kernel 2: QKV projection GEMM + fused per-head LayerNorm on K,V ----------
// m97 structure: BOTH operands via global_load_lds(16B). A is pre-cast bf16 (row-major MxK),
// B via Wt (NxK bf16). 128x128 tile, BK=64, 4 waves 2x2, 16x16x32 bf16 MFMA.
// XCD swizzle keeps the 8 N-tiles sharing an A strip on one XCD's L2.
__global__ __launch_bounds__(256, 4) void gemm_qkv_kernel(
    const ushort* __restrict__ Abf, const ushort* __restrict__ Wt,
    ushort* __restrict__ Cout,
    const float* __restrict__ ksc, const float* __restrict__ kbi,
    const float* __restrict__ vsc, const float* __restrict__ vbi) {
  __shared__ __align__(16) ushort As[128][64];
  __shared__ __align__(16) ushort Bs[128][64];

  const int bx0 = blockIdx.x;
  // bijective XCD swizzle (6144 = 8 * 768): siblings l=8m..8m+7 share bx0&7 == XCD
  const int bx = (bx0 & 7) * 768 + (bx0 >> 3);
  const int proj = bx >> 11;
  const int t2 = bx & 2047;
  const int mt = t2 >> 3;       // 256 M-tiles
  const int nt = t2 & 7;        // 8 N-tiles (fastest -> same A strip in 8 logical siblings)
  const ushort* A = Abf + (size_t)proj * PROJ_ELEMS;
  const ushort* Bw = Wt + (size_t)proj * 1024 * 1024;
  ushort* C = Cout + (size_t)proj * PROJ_ELEMS;
  const int m0 = mt * 128, n0 = nt * 128;
  const int tid = threadIdx.x;
  const int lane = tid & 63;
  const int wave = tid >> 6;
  const int wy = wave >> 1, wx = wave & 1;

  const f32x4 fzero = {0.0f, 0.0f, 0.0f, 0.0f};
  f32x4 acc[4][4];
#pragma unroll
  for (int i = 0; i < 4; i++)
#pragma unroll
    for (int j = 0; j < 4; j++) acc[i][j] = fzero;

  // DMA maps: seg = 8 rows x 64 cols bf16 = 1KB; lane l -> LDS base + 16*l,
  // global row = seg*8 + (l>>3), col = (l&7)*8. 16 segs per operand, 4 per wave.
  const int srow = lane >> 3;
  const int scol = (lane & 7) * 8;

  for (int k0 = 0; k0 < Kk; k0 += 64) {
#pragma unroll
    for (int j = 0; j < 4; j++) {
      const int seg = wave * 4 + j;
      async16(&As[seg * 8][0], A + (size_t)(m0 + seg * 8 + srow) * Kk + k0 + scol);
      async16(&Bs[seg * 8][0], Bw + (size_t)(n0 + seg * 8 + srow) * Kk + k0 + scol);
    }
    __syncthreads();
#pragma unroll
    for (int ks = 0; ks < 2; ks++) {
      bf16x8 af[4], bv[4];
#pragma unroll
      for (int i = 0; i < 4; i++)
        af[i] = *(const bf16x8*)&As[wy * 64 + i * 16 + (lane & 15)][ks * 32 + (lane >> 4) * 8];
#pragma unroll
      for (int j = 0; j < 4; j++)
        bv[j] = *(const bf16x8*)&Bs[wx * 64 + j * 16 + (lane & 15)][ks * 32 + (lane >> 4) * 8];
#pragma unroll
      for (int i = 0; i < 4; i++)
#pragma unroll
        for (int j = 0; j < 4; j++)
          acc[i][j] = __builtin_amdgcn_mfma_f32_16x16x32_bf16(af[i], bv[j], acc[i][j], 0, 0, 0);
    }
    __syncthreads();
  }

  // epilogue: C/D layout col=lane&15, row=(lane>>4)*4+reg
  if (proj == 0) {
#pragma unroll
    for (int i = 0; i < 4; i++) {
      const int rbase = m0 + wy * 64 + i * 16 + (lane >> 4) * 4;
#pragma unroll
      for (int j = 0; j < 4; j++) {
        const int col = n0 + wx * 64 + j * 16 + (lane & 15);
#pragma unroll
        for (int r = 0; r < 4; r++)
          C[(size_t)(rbase + r) * 1024 + col] = f2bf(acc[i][j][r]);
      }
    }
  } else {
    // fused per-head LayerNorm on the fp32 accumulators (K: proj==1, V: proj==2)
    const float* sc = (proj == 1) ? ksc : vsc;
    const float* bi = (proj == 1) ? kbi : vbi;
    const int h = (m0 >> 9) & 15;     // tile-uniform head index
    float scv[4], biv[4];
#pragma unroll
    for (int j = 0; j < 4; j++) {
      const int d = j * 16 + (lane & 15);      // = col & 63 (group aligned to 64)
      scv[j] = sc[h * 64 + d];
      biv[j] = bi[h * 64 + d];
    }
#pragma unroll
    for (int i = 0; i < 4; i++) {
      const int rbase = m0 + wy * 64 + i * 16 + (lane >> 4) * 4;
#pragma unroll
      for (int r = 0; r < 4; r++) {
        // one output row's 64-wide head group = 4 j-regs x 16 lanes of this subgroup
        float s = 0.f, sq = 0.f;
#pragma unroll
        for (int j = 0; j < 4; j++) {
          const float x = acc[i][j][r];
          s += x;
          sq += x * x;
        }
        s += __shfl_xor(s, 1); s += __shfl_xor(s, 2);
        s += __shfl_xor(s, 4); s += __shfl_xor(s, 8);
        sq += __shfl_xor(sq, 1); sq += __shfl_xor(sq, 2);
        sq += __shfl_xor(sq, 4); sq += __shfl_xor(sq, 8);
        const float mean = s * (1.0f / 64.0f);
        const float var = sq * (1.0f / 64.0f) - mean * mean;
        const float rs = rsqrtf(var + 1e-6f);
#pragma unroll
        for (int j = 0; j < 4; j++) {
          const int col = n0 + wx * 64 + j * 16 + (lane & 15);
          C[(size_t)(rbase + r) * 1024 + col] =
              f2bf((acc[i][j][r] - mean) * rs * scv[j] + biv[j]);
        }
      }
    }
  }
}

// ---------- legacy GEMM (fp32 A staged in-kernel) — fallback if ws too small ----------
__global__ __launch_bounds__(256, 3) void gemm_qkv_legacy(
    const float* __restrict__ Aq, const float* __restrict__ Ak,
    const float* __restrict__ Av, const ushort* __restrict__ Wt,
    ushort* __restrict__ Cout,
    const float* __restrict__ ksc, const float* __restrict__ kbi,
    const float* __restrict__ vsc, const float* __restrict__ vbi) {
  __shared__ __align__(16) ushort As[128][64];
  __shared__ __align__(16) ushort Bs[128][64];

  const int bx0 = blockIdx.x;
  const int bx = (bx0 & 7) * 768 + (bx0 >> 3);
  const int proj = bx >> 11;
  const int t2 = bx & 2047;
  const int mt = t2 >> 3;
  const int nt = t2 & 7;
  const float* A = (proj == 0) ? Aq : ((proj == 1) ? Ak : Av);
  const ushort* Bw = Wt + (size_t)proj * 1024 * 1024;
  ushort* C = Cout + (size_t)proj * PROJ_ELEMS;
  const int m0 = mt * 128, n0 = nt * 128;
  const int tid = threadIdx.x;
  const int lane = tid & 63;
  const int wave = tid >> 6;
  const int wy = wave >> 1, wx = wave & 1;
  const int ar = tid >> 3;
  const int ac = (tid & 7) * 8;
  const float* Abase = A + (size_t)m0 * Kk;

  const f32x4 fzero = {0.0f, 0.0f, 0.0f, 0.0f};
  f32x4 acc[4][4];
#pragma unroll
  for (int i = 0; i < 4; i++)
#pragma unroll
    for (int j = 0; j < 4; j++) acc[i][j] = fzero;

  for (int k0 = 0; k0 < Kk; k0 += 64) {
#pragma unroll
    for (int j = 0; j < 4; j++) {
      const int seg = wave * 4 + j;
      const int brow = seg * 8 + (lane >> 3);
      const int bcol = (lane & 7) * 8;
      async16(&Bs[seg * 8][0], Bw + (size_t)(n0 + brow) * Kk + k0 + bcol);
    }
#pragma unroll
    for (int i = 0; i < 4; i++) {
      const int row = ar + i * 32;
      const float* src = Abase + (size_t)row * Kk + k0 + ac;
      const float4 f0 = *(const float4*)src;
      const float4 f1 = *(const float4*)(src + 4);
      uint4 v;
      v.x = pack2(f0.x, f0.y);
      v.y = pack2(f0.z, f0.w);
      v.z = pack2(f1.x, f1.y);
      v.w = pack2(f1.z, f1.w);
      *(uint4*)&As[row][ac] = v;
    }
    __syncthreads();
#pragma unroll
    for (int ks = 0; ks < 2; ks++) {
      bf16x8 af[4], bv[4];
#pragma unroll
      for (int i = 0; i < 4; i++)
        af[i] = *(const bf16x8*)&As[wy * 64 + i * 16 + (lane & 15)][ks * 32 + (lane >> 4) * 8];
#pragma unroll
      for (int j = 0; j < 4; j++)
        bv[j] = *(const bf16x8*)&Bs[wx * 64 + j * 16 + (lane & 15)][ks * 32 + (lane >> 4) * 8];
#pragma unroll
      for (int i = 0; i < 4; i++)
#pragma unroll
        for (int j = 0; j < 4; j++)
          acc[i][j] = __builtin_amdgcn_mfma_f32_16x16x32_bf16(af[i], bv[j], acc[i][j], 0, 0, 0);
    }
    __syncthreads();
  }

  if (proj == 0) {
#pragma unroll
    for (int i = 0; i < 4; i++) {
      const int rbase = m0 + wy * 64 + i * 16 + (lane >> 4) * 4;
#pragma unroll
      for (int j = 0; j < 4; j++) {
        const int col = n0 + wx * 64 + j * 16 + (lane & 15);
#pragma unroll
        for (int r = 0; r < 4; r++)
          C[(size_t)(rbase + r) * 1024 + col] = f2bf(acc[i][j][r]);
      }
    }
  } else {
    const float* sc = (proj == 1) ? ksc : vsc;
    const float* bi = (proj == 1) ? kbi : vbi;
    const int h = (m0 >> 9) & 15;
    float scv[4], biv[4];
#pragma unroll
    for (int j = 0; j < 4; j++) {
      const int d = j * 16 + (lane & 15);
      scv[j] = sc[h * 64 + d];
      biv[j] = bi[h * 64 + d];
    }
#pragma unroll
    for (int i = 0; i < 4; i++) {
      const int rbase = m0 + wy * 64 + i * 16 + (lane >> 4) * 4;
#pragma unroll
      for (int r = 0; r < 4; r++) {
        float s = 0.f, sq = 0.f;
#pragma unroll
        for (int j = 0; j < 4; j++) {
          const float x = acc[i][j][r];
          s += x;
          sq += x * x;
        }
        s += __shfl_xor(s, 1); s += __shfl_xor(s, 2);
        s += __shfl_xor(s, 4); s += __shfl_xor(s, 8);
        sq += __shfl_xor(sq, 1); sq += __shfl_xor(sq, 2);
        sq += __shfl_xor(sq, 4); sq += __shfl_xor(sq, 8);
        const float mean = s * (1.0f / 64.0f);
        const float var = sq * (1.0f / 64.0f) - mean * mean;
        const float rs = rsqrtf(var + 1e-6f);
#pragma unroll
        for (int j = 0; j < 4; j++) {
          const int col = n0 + wx * 64 + j * 16 + (lane & 15);
          C[(size_t)(rbase + r) * 1024 + col] =
              f2bf((acc[i][j][r] - mean) * rs * scv[j] + biv[j]);
        }
      }
    }
  }
}

// ---------- kernel 3: p_raw += K^T V partials (split-K over 16 chunks of 512 rows) ----------
__global__ __launch_bounds__(256) void pattn_kernel(const ushort* __restrict__ kp,
                                                    const ushort* __restrict__ vp,
                                                    float* __restrict__ praw) {
  __shared__ __align__(16) ushort kT[64][72];   // (d, n) transposed, pad 72 breaks bank stride
  __shared__ __align__(16) ushort vT[64][72];   // (e, n)
  const int bh = blockIdx.x >> 4;
  const int nc = blockIdx.x & 15;
  const ushort* kb = kp + ((size_t)bh << 19) + (size_t)nc * 32768;
  const ushort* vb = vp + ((size_t)bh << 19) + (size_t)nc * 32768;
  const int tid = threadIdx.x;
  const int lane = tid & 63;
  const int wave = tid >> 6;
  const int d0 = wave * 16;
  const f32x4 fzero = {0.0f, 0.0f, 0.0f, 0.0f};
  f32x4 acc[4];
#pragma unroll
  for (int e = 0; e < 4; e++) acc[e] = fzero;

  for (int c = 0; c < 8; c++) {   // 8 sub-chunks of 64 n-rows
    const ushort* kc = kb + c * 4096;
    const ushort* vc = vb + c * 4096;
    // lane = n index; wave covers d0..d0+15
    const uint4 ka = *(const uint4*)(kc + (size_t)lane * 64 + d0);
    const uint4 ka2 = *(const uint4*)(kc + (size_t)lane * 64 + d0 + 8);
    const uint4 va = *(const uint4*)(vc + (size_t)lane * 64 + d0);
    const uint4 va2 = *(const uint4*)(vc + (size_t)lane * 64 + d0 + 8);
    __syncthreads();   // previous compute done before overwriting LDS
    const uint32_t* kw = (const uint32_t*)&ka;
    const uint32_t* kw2 = (const uint32_t*)&ka2;
    const uint32_t* vw = (const uint32_t*)&va;
    const uint32_t* vw2 = (const uint32_t*)&va2;
#pragma unroll
    for (int j = 0; j < 4; j++) {   // all lanes same d -> contiguous 2B writes, conflict-free
      kT[d0 + 2 * j][lane] = (ushort)(kw[j] & 0xffffu);
      kT[d0 + 2 * j + 1][lane] = (ushort)(kw[j] >> 16);
      kT[d0 + 8 + 2 * j][lane] = (ushort)(kw2[j] & 0xffffu);
      kT[d0 + 8 + 2 * j + 1][lane] = (ushort)(kw2[j] >> 16);
      vT[d0 + 2 * j][lane] = (ushort)(vw[j] & 0xffffu);
      vT[d0 + 2 * j + 1][lane] = (ushort)(vw[j] >> 16);
      vT[d0 + 8 + 2 * j][lane] = (ushort)(vw2[j] & 0xffffu);
      vT[d0 + 8 + 2 * j + 1][lane] = (ushort)(vw2[j] >> 16);
    }
    __syncthreads();
#pragma unroll
    for (int ks = 0; ks < 2; ks++) {
      const bf16x8 af = *(const bf16x8*)&kT[wave * 16 + (lane & 15)][ks * 32 + (lane >> 4) * 8];
#pragma unroll
      for (int e = 0; e < 4; e++) {
        const bf16x8 bv = *(const bf16x8*)&vT[e * 16 + (lane & 15)][ks * 32 + (lane >> 4) * 8];
        acc[e] = __builtin_amdgcn_mfma_f32_16x16x32_bf16(af, bv, acc[e], 0, 0, 0);
      }
    }
  }
#pragma unroll
  for (int e = 0; e < 4; e++)
#pragma unroll
    for (int r = 0; r < 4; r++) {
      const int drow = wave * 16 + (lane >> 4) * 4 + r;
      const int ecol = e * 16 + (lane & 15);
      atomicAdd(&praw[(size_t)bh * 4096 + drow * 64 + ecol], acc[e][r]);
    }
}

// ---------- kernel 4: p_out = p_raw / 8192 ----------
__global__ __launch_bounds__(256) void scalep_kernel(const float* __restrict__ praw,
                                                     float* __restrict__ pout) {
  const int i = blockIdx.x * 256 + threadIdx.x;
  pout[i] = praw[i] * (1.0f / 8192.0f);
}

// ---------- kernel 5: att = Q * (p_raw/8192) per (b,h); A-frags straight from global ----------
__global__ __launch_bounds__(256) void outgemm_kernel(const ushort* __restrict__ qp,
                                                      const float* __restrict__ praw,
                                                      float* __restrict__ xout) {
  __shared__ __align__(16) ushort pT[64][72];   // (e, d) so B-frags are d-contiguous
  const int bh = blockIdx.x >> 5;
  const int mc = blockIdx.x & 31;               // 32 chunks of 256 rows
  const ushort* qb = qp + ((size_t)bh << 19) + (size_t)mc * 256 * 64;
  float* ob = xout + ((size_t)bh << 19) + (size_t)mc * 256 * 64;
  const float* pb = praw + (size_t)bh * 4096;
  const int tid = threadIdx.x;
  const int lane = tid & 63;
  const int wave = tid >> 6;
  for (int i = tid; i < 4096; i += 256) {
    const int d = i >> 6, e = i & 63;
    pT[e][d] = f2bf(pb[i] * (1.0f / 8192.0f));
  }
  __syncthreads();
  bf16x8 bv[4][2];
#pragma unroll
  for (int e = 0; e < 4; e++)
#pragma unroll
    for (int ks = 0; ks < 2; ks++)
      bv[e][ks] = *(const bf16x8*)&pT[e * 16 + (lane & 15)][ks * 32 + (lane >> 4) * 8];
  const f32x4 fzero = {0.0f, 0.0f, 0.0f, 0.0f};
  for (int it = 0; it < 4; it++) {
    const int rbase = it * 64 + wave * 16;
    const ushort* qrow = qb + (size_t)rbase * 64;
    const bf16x8 a0 = *(const bf16x8*)(qrow + (size_t)(lane & 15) * 64 + (lane >> 4) * 8);
    const bf16x8 a1 = *(const bf16x8*)(qrow + (size_t)(lane & 15) * 64 + (lane >> 4) * 8 + 32);
    f32x4 acc[4];
#pragma unroll
    for (int e = 0; e < 4; e++) acc[e] = fzero;
#pragma unroll
    for (int e = 0; e < 4; e++) {
      acc[e] = __builtin_amdgcn_mfma_f32_16x16x32_bf16(a0, bv[e][0], acc[e], 0, 0, 0);
      acc[e] = __builtin_amdgcn_mfma_f32_16x16x32_bf16(a1, bv[e][1], acc[e], 0, 0, 0);
    }
#pragma unroll
    for (int e = 0; e < 4; e++)
#pragma unroll
      for (int r = 0; r < 4; r++)
        ob[(size_t)(rbase + (lane >> 4) * 4 + r) * 64 + e * 16 + (lane & 15)] = acc[e][r];
  }
}

extern "C" void kernel_launch(void* const* d_in, const int* in_sizes, int n_in,
                              void* d_out, int out_size, void* d_ws, size_t ws_size,
                              hipStream_t stream) {
  const float* q_in = (const float*)d_in[0];
  const float* k_in = (const float*)d_in[1];
  const float* v_in = (const float*)d_in[2];
  const float* Wq = (const float*)d_in[3];
  const float* Wk = (const float*)d_in[4];
  const float* Wv = (const float*)d_in[5];
  const float* ksc = (const float*)d_in[6];
  const float* kbi = (const float*)d_in[7];
  const float* vsc = (const float*)d_in[8];
  const float* vbi = (const float*)d_in[9];

  float* att = (float*)d_out;                    // 33554432 fp32
  float* pout = att + (size_t)PROJ_ELEMS;        // 262144 fp32

  // new layout: a_bf (3x64MB) | q/k/v proj bf16 (3x64MB) | Wt bf16 (3x2MB) | p_raw fp32 (1MB)
  const size_t need_new = (size_t)3 * PROJ_ELEMS * 2 * 2   // a_bf + proj
                        + (size_t)3 * 1024 * 1024 * 2      // Wt
                        + (size_t)262144 * 4;              // praw
  if (ws_size >= need_new) {
    ushort* a_bf = (ushort*)d_ws;
    ushort* q_proj = a_bf + (size_t)3 * PROJ_ELEMS;
    ushort* k_proj = q_proj + (size_t)PROJ_ELEMS;
    ushort* v_proj = k_proj + (size_t)PROJ_ELEMS;
    ushort* wtb = v_proj + (size_t)PROJ_ELEMS;
    float* praw = (float*)(wtb + (size_t)3 * 1024 * 1024);

    wt_kernel<<<768, 256, 0, stream>>>(Wq, Wk, Wv, wtb);
    cast_kernel<<<6144, 256, 0, stream>>>(q_in, k_in, v_in, a_bf);
    gemm_qkv_kernel<<<6144, 256, 0, stream>>>(a_bf, wtb, q_proj, ksc, kbi, vsc, vbi);
    (void)hipMemsetAsync(praw, 0, (size_t)Bb * Hh * 64 * 64 * sizeof(float), stream);
    pattn_kernel<<<1024, 256, 0, stream>>>(k_proj, v_proj, praw);
    scalep_kernel<<<1024, 256, 0, stream>>>(praw, pout);
    outgemm_kernel<<<2048, 256, 0, stream>>>(q_proj, praw, att);
  } else {
    // legacy layout: proj (3x64MB) | Wt | praw
    ushort* q_proj = (ushort*)d_ws;
    ushort* k_proj = q_proj + (size_t)PROJ_ELEMS;
    ushort* v_proj = k_proj + (size_t)PROJ_ELEMS;
    ushort* wtb = v_proj + (size_t)PROJ_ELEMS;
    float* praw = (float*)(wtb + (size_t)3 * 1024 * 1024);

    wt_kernel<<<768, 256, 0, stream>>>(Wq, Wk, Wv, wtb);
    gemm_qkv_legacy<<<6144, 256, 0, stream>>>(q_in, k_in, v_in, wtb, q_proj,
                                              ksc, kbi, vsc, vbi);
    (void)hipMemsetAsync(praw, 0, (size_t)Bb * Hh * 64 * 64 * sizeof(float), stream);
    pattn_kernel<<<1024, 256, 0, stream>>>(k_proj, v_proj, praw);
    scalep_kernel<<<1024, 256, 0, stream>>>(praw, pout);
    outgemm_kernel<<<2048, 256, 0, stream>>>(q_proj, praw, att);
  }
}

// Round 3
// 745.191 us; speedup vs baseline: 1.2038x; 1.0530x over previous
//
#include <hip/hip_runtime.h>
#include <hip/hip_bf16.h>
#include <stdint.h>

#define DEVI __device__ __forceinline__

typedef __attribute__((ext_vector_type(8))) short bf16x8;   // 8 bf16 = 4 VGPRs
typedef __attribute__((ext_vector_type(4))) float f32x4;    // MFMA acc

static constexpr int Bb = 4, Ss = 8192, Ff = 1024, Hh = 16, Dd = 64;
static constexpr int Mm = Bb * Ss;                 // 32768 rows of the projection GEMMs
static constexpr int Kk = Ff;                      // 1024
static constexpr int PROJ_ELEMS = Mm * Ff;         // 33554432 per projection

// ---------- small helpers ----------
DEVI ushort f2bf(float f) {            // fp32 -> bf16 RNE (manual, finite inputs)
  uint32_t u = __builtin_bit_cast(uint32_t, f);
  u += 0x7fffu + ((u >> 16) & 1u);
  return (ushort)(u >> 16);
}
DEVI float bf2f(ushort u) { return __builtin_bit_cast(float, (uint32_t)u << 16); }

DEVI uint32_t pack2(float a, float b) {  // 2×fp32 -> packed bf16x2 (manual RNE)
  return (uint32_t)f2bf(a) | ((uint32_t)f2bf(b) << 16);
}

DEVI void async16(void* lds, const void* g) {  // 16B/lane global->LDS DMA
  __builtin_amdgcn_global_load_lds((const __attribute__((address_space(1))) void*)g,
                                   (__attribute__((address_space(3))) void*)lds,
                                   16, 0, 0);
}

// ---------- kernel 0: fp32 -> bf16 streaming cast of q/k/v activations ----------
__global__ __launch_bounds__(256) void cast_kernel(const float* __restrict__ q,
                                                   const float* __restrict__ k,
                                                   const float* __restrict__ v,
                                                   ushort* __restrict__ abf) {
  const int b = blockIdx.x;
  const int proj = b >> 11;                      // 2048 blocks per tensor
  const float* src = (proj == 0) ? q : ((proj == 1) ? k : v);
  ushort* dst = abf + (size_t)proj * PROJ_ELEMS;
  const int tid0 = (b & 2047) * 256 + threadIdx.x;   // 524288 threads per tensor
#pragma unroll
  for (int p = 0; p < 8; ++p) {
    const size_t i = ((size_t)p * 524288 + (size_t)tid0) * 8;
    const float4 f0 = *(const float4*)(src + i);
    const float4 f1 = *(const float4*)(src + i + 4);
    uint4 o;
    o.x = pack2(f0.x, f0.y);
    o.y = pack2(f0.z, f0.w);
    o.z = pack2(f1.x, f1.y);
    o.w = pack2(f1.z, f1.w);
    *(uint4*)(dst + i) = o;
  }
}

// ---------- kernel 1: W (K,N) fp32 -> Wt (N,K) bf16 ----------
__global__ __launch_bounds__(256) void wt_kernel(const float* __restrict__ Wq,
                                                 const float* __restrict__ Wk,
                                                 const float* __restrict__ Wv,
                                                 ushort* __restrict__ wt) {
  __shared__ float tile[64][65];
  int b = blockIdx.x;
  const int w = b >> 8; b &= 255;
  const int kt = b >> 4, nt = b & 15;         // 16x16 tiles of 64x64
  const float* Wsrc = (w == 0) ? Wq : ((w == 1) ? Wk : Wv);
  ushort* dst = wt + (size_t)w * 1024 * 1024;
  const int t = threadIdx.x;
  const int r = t >> 6, c = t & 63;
#pragma unroll
  for (int i = 0; i < 16; i++) {
    const int kk = kt * 64 + r + i * 4;
    tile[r + i * 4][c] = Wsrc[(size_t)kk * 1024 + nt * 64 + c];
  }
  __syncthreads();
#pragma unroll
  for (int i = 0; i < 16; i++) {
    const int nn = nt * 64 + r + i * 4;
    dst[(size_t)nn * 1024 + kt * 64 + c] = f2bf(tile[c][r + i * 4]);
  }
}

// ---------- kernel 2: QKV projection GEMM + fused per-head LayerNorm on K,V ----------
// m97 structure + T2 XOR-swizzle: LDS stays linear (global_load_lds dest is linear),
// the permutation lives in the per-lane GLOBAL source address and in the ds_read
// address (rule #21: inverse-swz source + swz read, same involution).
// Swizzle: physical 16B-chunk = logical chunk ^ ((row>>1)&7) -> fragment reads
// (16 lanes, consecutive rows, fixed col) spread over 8 bank groups (2-way = free).
__global__ __launch_bounds__(256, 4) void gemm_qkv_kernel(
    const ushort* __restrict__ Abf, const ushort* __restrict__ Wt,
    ushort* __restrict__ Cout,
    const float* __restrict__ ksc, const float* __restrict__ kbi,
    const float* __restrict__ vsc, const float* __restrict__ vbi) {
  __shared__ __align__(16) ushort As[128][64];
  __shared__ __align__(16) ushort Bs[128][64];

  const int bx0 = blockIdx.x;
  // bijective XCD swizzle (6144 = 8 * 768): siblings l=8m..8m+7 share bx0&7 == XCD
  const int bx = (bx0 & 7) * 768 + (bx0 >> 3);
  const int proj = bx >> 11;
  const int t2 = bx & 2047;
  const int mt = t2 >> 3;       // 256 M-tiles
  const int nt = t2 & 7;        // 8 N-tiles (fastest -> same A strip in 8 logical siblings)
  const ushort* A = Abf + (size_t)proj * PROJ_ELEMS;
  const ushort* Bw = Wt + (size_t)proj * 1024 * 1024;
  ushort* C = Cout + (size_t)proj * PROJ_ELEMS;
  const int m0 = mt * 128, n0 = nt * 128;
  const int tid = threadIdx.x;
  const int lane = tid & 63;
  const int wave = tid >> 6;
  const int wy = wave >> 1, wx = wave & 1;

  const f32x4 fzero = {0.0f, 0.0f, 0.0f, 0.0f};
  f32x4 acc[4][4];
#pragma unroll
  for (int i = 0; i < 4; i++)
#pragma unroll
    for (int j = 0; j < 4; j++) acc[i][j] = fzero;

  // DMA map: seg = 8 rows x 64 cols; lane l -> LDS chunk (row = seg*8 + (l>>3),
  // phys chunk c = l&7). Source fetches logical chunk c ^ ((row>>1)&7).
  const int srow = lane >> 3;
  const int schunk = lane & 7;
  const int q4 = lane >> 4;        // fragment quarter

  for (int k0 = 0; k0 < Kk; k0 += 64) {
#pragma unroll
    for (int j = 0; j < 4; j++) {
      const int seg = wave * 4 + j;
      const int row = seg * 8 + srow;
      const int sw = (schunk ^ ((row >> 1) & 7)) * 8;
      async16(&As[seg * 8][0], A + (size_t)(m0 + row) * Kk + k0 + sw);
      async16(&Bs[seg * 8][0], Bw + (size_t)(n0 + row) * Kk + k0 + sw);
    }
    __syncthreads();
#pragma unroll
    for (int ks = 0; ks < 2; ks++) {
      bf16x8 af[4], bv[4];
#pragma unroll
      for (int i = 0; i < 4; i++) {
        const int row = wy * 64 + i * 16 + (lane & 15);
        const int pc = ((ks * 4 + q4) ^ ((row >> 1) & 7)) * 8;
        af[i] = *(const bf16x8*)&As[row][pc];
      }
#pragma unroll
      for (int j = 0; j < 4; j++) {
        const int row = wx * 64 + j * 16 + (lane & 15);
        const int pc = ((ks * 4 + q4) ^ ((row >> 1) & 7)) * 8;
        bv[j] = *(const bf16x8*)&Bs[row][pc];
      }
      __builtin_amdgcn_s_setprio(1);
#pragma unroll
      for (int i = 0; i < 4; i++)
#pragma unroll
        for (int j = 0; j < 4; j++)
          acc[i][j] = __builtin_amdgcn_mfma_f32_16x16x32_bf16(af[i], bv[j], acc[i][j], 0, 0, 0);
      __builtin_amdgcn_s_setprio(0);
    }
    __syncthreads();
  }

  // epilogue: C/D layout col=lane&15, row=(lane>>4)*4+reg
  if (proj == 0) {
#pragma unroll
    for (int i = 0; i < 4; i++) {
      const int rbase = m0 + wy * 64 + i * 16 + (lane >> 4) * 4;
#pragma unroll
      for (int j = 0; j < 4; j++) {
        const int col = n0 + wx * 64 + j * 16 + (lane & 15);
#pragma unroll
        for (int r = 0; r < 4; r++)
          C[(size_t)(rbase + r) * 1024 + col] = f2bf(acc[i][j][r]);
      }
    }
  } else {
    // fused per-head LayerNorm on the fp32 accumulators (K: proj==1, V: proj==2)
    const float* sc = (proj == 1) ? ksc : vsc;
    const float* bi = (proj == 1) ? kbi : vbi;
    const int h = (m0 >> 9) & 15;     // tile-uniform head index
    float scv[4], biv[4];
#pragma unroll
    for (int j = 0; j < 4; j++) {
      const int d = j * 16 + (lane & 15);      // = col & 63 (group aligned to 64)
      scv[j] = sc[h * 64 + d];
      biv[j] = bi[h * 64 + d];
    }
#pragma unroll
    for (int i = 0; i < 4; i++) {
      const int rbase = m0 + wy * 64 + i * 16 + (lane >> 4) * 4;
#pragma unroll
      for (int r = 0; r < 4; r++) {
        float s = 0.f, sq = 0.f;
#pragma unroll
        for (int j = 0; j < 4; j++) {
          const float x = acc[i][j][r];
          s += x;
          sq += x * x;
        }
        s += __shfl_xor(s, 1); s += __shfl_xor(s, 2);
        s += __shfl_xor(s, 4); s += __shfl_xor(s, 8);
        sq += __shfl_xor(sq, 1); sq += __shfl_xor(sq, 2);
        sq += __shfl_xor(sq, 4); sq += __shfl_xor(sq, 8);
        const float mean = s * (1.0f / 64.0f);
        const float var = sq * (1.0f / 64.0f) - mean * mean;
        const float rs = rsqrtf(var + 1e-6f);
#pragma unroll
        for (int j = 0; j < 4; j++) {
          const int col = n0 + wx * 64 + j * 16 + (lane & 15);
          C[(size_t)(rbase + r) * 1024 + col] =
              f2bf((acc[i][j][r] - mean) * rs * scv[j] + biv[j]);
        }
      }
    }
  }
}

// ---------- legacy GEMM (fp32 A staged in-kernel) — fallback if ws too small ----------
__global__ __launch_bounds__(256, 3) void gemm_qkv_legacy(
    const float* __restrict__ Aq, const float* __restrict__ Ak,
    const float* __restrict__ Av, const ushort* __restrict__ Wt,
    ushort* __restrict__ Cout,
    const float* __restrict__ ksc, const float* __restrict__ kbi,
    const float* __restrict__ vsc, const float* __restrict__ vbi) {
  __shared__ __align__(16) ushort As[128][64];
  __shared__ __align__(16) ushort Bs[128][64];

  const int bx0 = blockIdx.x;
  const int bx = (bx0 & 7) * 768 + (bx0 >> 3);
  const int proj = bx >> 11;
  const int t2 = bx & 2047;
  const int mt = t2 >> 3;
  const int nt = t2 & 7;
  const float* A = (proj == 0) ? Aq : ((proj == 1) ? Ak : Av);
  const ushort* Bw = Wt + (size_t)proj * 1024 * 1024;
  ushort* C = Cout + (size_t)proj * PROJ_ELEMS;
  const int m0 = mt * 128, n0 = nt * 128;
  const int tid = threadIdx.x;
  const int lane = tid & 63;
  const int wave = tid >> 6;
  const int wy = wave >> 1, wx = wave & 1;
  const int ar = tid >> 3;
  const int ac = (tid & 7) * 8;
  const float* Abase = A + (size_t)m0 * Kk;

  const f32x4 fzero = {0.0f, 0.0f, 0.0f, 0.0f};
  f32x4 acc[4][4];
#pragma unroll
  for (int i = 0; i < 4; i++)
#pragma unroll
    for (int j = 0; j < 4; j++) acc[i][j] = fzero;

  for (int k0 = 0; k0 < Kk; k0 += 64) {
#pragma unroll
    for (int j = 0; j < 4; j++) {
      const int seg = wave * 4 + j;
      const int brow = seg * 8 + (lane >> 3);
      const int bcol = (lane & 7) * 8;
      async16(&Bs[seg * 8][0], Bw + (size_t)(n0 + brow) * Kk + k0 + bcol);
    }
#pragma unroll
    for (int i = 0; i < 4; i++) {
      const int row = ar + i * 32;
      const float* src = Abase + (size_t)row * Kk + k0 + ac;
      const float4 f0 = *(const float4*)src;
      const float4 f1 = *(const float4*)(src + 4);
      uint4 v;
      v.x = pack2(f0.x, f0.y);
      v.y = pack2(f0.z, f0.w);
      v.z = pack2(f1.x, f1.y);
      v.w = pack2(f1.z, f1.w);
      *(uint4*)&As[row][ac] = v;
    }
    __syncthreads();
#pragma unroll
    for (int ks = 0; ks < 2; ks++) {
      bf16x8 af[4], bv[4];
#pragma unroll
      for (int i = 0; i < 4; i++)
        af[i] = *(const bf16x8*)&As[wy * 64 + i * 16 + (lane & 15)][ks * 32 + (lane >> 4) * 8];
#pragma unroll
      for (int j = 0; j < 4; j++)
        bv[j] = *(const bf16x8*)&Bs[wx * 64 + j * 16 + (lane & 15)][ks * 32 + (lane >> 4) * 8];
#pragma unroll
      for (int i = 0; i < 4; i++)
#pragma unroll
        for (int j = 0; j < 4; j++)
          acc[i][j] = __builtin_amdgcn_mfma_f32_16x16x32_bf16(af[i], bv[j], acc[i][j], 0, 0, 0);
    }
    __syncthreads();
  }

  if (proj == 0) {
#pragma unroll
    for (int i = 0; i < 4; i++) {
      const int rbase = m0 + wy * 64 + i * 16 + (lane >> 4) * 4;
#pragma unroll
      for (int j = 0; j < 4; j++) {
        const int col = n0 + wx * 64 + j * 16 + (lane & 15);
#pragma unroll
        for (int r = 0; r < 4; r++)
          C[(size_t)(rbase + r) * 1024 + col] = f2bf(acc[i][j][r]);
      }
    }
  } else {
    const float* sc = (proj == 1) ? ksc : vsc;
    const float* bi = (proj == 1) ? kbi : vbi;
    const int h = (m0 >> 9) & 15;
    float scv[4], biv[4];
#pragma unroll
    for (int j = 0; j < 4; j++) {
      const int d = j * 16 + (lane & 15);
      scv[j] = sc[h * 64 + d];
      biv[j] = bi[h * 64 + d];
    }
#pragma unroll
    for (int i = 0; i < 4; i++) {
      const int rbase = m0 + wy * 64 + i * 16 + (lane >> 4) * 4;
#pragma unroll
      for (int r = 0; r < 4; r++) {
        float s = 0.f, sq = 0.f;
#pragma unroll
        for (int j = 0; j < 4; j++) {
          const float x = acc[i][j][r];
          s += x;
          sq += x * x;
        }
        s += __shfl_xor(s, 1); s += __shfl_xor(s, 2);
        s += __shfl_xor(s, 4); s += __shfl_xor(s, 8);
        sq += __shfl_xor(sq, 1); sq += __shfl_xor(sq, 2);
        sq += __shfl_xor(sq, 4); sq += __shfl_xor(sq, 8);
        const float mean = s * (1.0f / 64.0f);
        const float var = sq * (1.0f / 64.0f) - mean * mean;
        const float rs = rsqrtf(var + 1e-6f);
#pragma unroll
        for (int j = 0; j < 4; j++) {
          const int col = n0 + wx * 64 + j * 16 + (lane & 15);
          C[(size_t)(rbase + r) * 1024 + col] =
              f2bf((acc[i][j][r] - mean) * rs * scv[j] + biv[j]);
        }
      }
    }
  }
}

// ---------- kernel 3: stage-1 K^T V partials, NO atomics, prefetched loads ----------
// 1024 blocks = 64 (b,h) x 16 n-chunks of 512 rows; each block writes its own
// 4096-float partial to praw2[nc][bh][4096]. Next chunk's global loads issue
// under the current chunk's barrier+MFMA (latency hidden).
__global__ __launch_bounds__(256) void pattn_kernel(const ushort* __restrict__ kp,
                                                    const ushort* __restrict__ vp,
                                                    float* __restrict__ praw2) {
  __shared__ __align__(16) ushort kT[64][72];   // (d, n) transposed, pad 72 breaks bank stride
  __shared__ __align__(16) ushort vT[64][72];   // (e, n)
  const int bh = blockIdx.x >> 4;
  const int nc = blockIdx.x & 15;
  const ushort* kb = kp + ((size_t)bh << 19) + (size_t)nc * 32768;
  const ushort* vb = vp + ((size_t)bh << 19) + (size_t)nc * 32768;
  const int tid = threadIdx.x;
  const int lane = tid & 63;
  const int wave = tid >> 6;
  const int d0 = wave * 16;
  const f32x4 fzero = {0.0f, 0.0f, 0.0f, 0.0f};
  f32x4 acc[4];
#pragma unroll
  for (int e = 0; e < 4; e++) acc[e] = fzero;

  const size_t loff = (size_t)lane * 64 + d0;
  uint4 ka  = *(const uint4*)(kb + loff);
  uint4 ka2 = *(const uint4*)(kb + loff + 8);
  uint4 va  = *(const uint4*)(vb + loff);
  uint4 va2 = *(const uint4*)(vb + loff + 8);

  for (int c = 0; c < 8; c++) {   // 8 sub-chunks of 64 n-rows
    __syncthreads();   // previous MFMA done reading LDS
    const uint32_t* kw = (const uint32_t*)&ka;
    const uint32_t* kw2 = (const uint32_t*)&ka2;
    const uint32_t* vw = (const uint32_t*)&va;
    const uint32_t* vw2 = (const uint32_t*)&va2;
#pragma unroll
    for (int j = 0; j < 4; j++) {   // all lanes same d -> contiguous 2B writes, conflict-free
      kT[d0 + 2 * j][lane] = (ushort)(kw[j] & 0xffffu);
      kT[d0 + 2 * j + 1][lane] = (ushort)(kw[j] >> 16);
      kT[d0 + 8 + 2 * j][lane] = (ushort)(kw2[j] & 0xffffu);
      kT[d0 + 8 + 2 * j + 1][lane] = (ushort)(kw2[j] >> 16);
      vT[d0 + 2 * j][lane] = (ushort)(vw[j] & 0xffffu);
      vT[d0 + 2 * j + 1][lane] = (ushort)(vw[j] >> 16);
      vT[d0 + 8 + 2 * j][lane] = (ushort)(vw2[j] & 0xffffu);
      vT[d0 + 8 + 2 * j + 1][lane] = (ushort)(vw2[j] >> 16);
    }
    if (c < 7) {                    // prefetch next chunk (consumed next iter's writes)
      const size_t noff = loff + (size_t)(c + 1) * 4096;
      ka  = *(const uint4*)(kb + noff);
      ka2 = *(const uint4*)(kb + noff + 8);
      va  = *(const uint4*)(vb + noff);
      va2 = *(const uint4*)(vb + noff + 8);
    }
    __syncthreads();
#pragma unroll
    for (int ks = 0; ks < 2; ks++) {
      const bf16x8 af = *(const bf16x8*)&kT[wave * 16 + (lane & 15)][ks * 32 + (lane >> 4) * 8];
#pragma unroll
      for (int e = 0; e < 4; e++) {
        const bf16x8 bv = *(const bf16x8*)&vT[e * 16 + (lane & 15)][ks * 32 + (lane >> 4) * 8];
        acc[e] = __builtin_amdgcn_mfma_f32_16x16x32_bf16(af, bv, acc[e], 0, 0, 0);
      }
    }
  }
  float* out = praw2 + ((size_t)nc * 64 + bh) * 4096;
#pragma unroll
  for (int e = 0; e < 4; e++)
#pragma unroll
    for (int r = 0; r < 4; r++) {
      const int drow = wave * 16 + (lane >> 4) * 4 + r;
      const int ecol = e * 16 + (lane & 15);
      out[drow * 64 + ecol] = acc[e][r];
    }
}

// ---------- kernel 4: reduce 16 partials -> p_out (already scaled by 1/8192) ----------
__global__ __launch_bounds__(256) void preduce_kernel(const float* __restrict__ praw2,
                                                      float* __restrict__ pout) {
  const int i = blockIdx.x * 256 + threadIdx.x;    // 0..262143
  float s = 0.f;
#pragma unroll
  for (int p = 0; p < 16; ++p) s += praw2[(size_t)p * 262144 + i];
  pout[i] = s * (1.0f / 8192.0f);
}

// ---------- kernel 5: att = Q * p_out per (b,h); A-frags straight from global ----------
__global__ __launch_bounds__(256) void outgemm_kernel(const ushort* __restrict__ qp,
                                                      const float* __restrict__ pout,
                                                      float* __restrict__ xout) {
  __shared__ __align__(16) ushort pT[64][72];   // (e, d) so B-frags are d-contiguous
  const int bh = blockIdx.x >> 5;
  const int mc = blockIdx.x & 31;               // 32 chunks of 256 rows
  const ushort* qb = qp + ((size_t)bh << 19) + (size_t)mc * 256 * 64;
  float* ob = xout + ((size_t)bh << 19) + (size_t)mc * 256 * 64;
  const float* pb = pout + (size_t)bh * 4096;
  const int tid = threadIdx.x;
  const int lane = tid & 63;
  const int wave = tid >> 6;
  for (int i = tid; i < 4096; i += 256) {
    const int d = i >> 6, e = i & 63;
    pT[e][d] = f2bf(pb[i]);                     // pout already scaled
  }
  __syncthreads();
  bf16x8 bv[4][2];
#pragma unroll
  for (int e = 0; e < 4; e++)
#pragma unroll
    for (int ks = 0; ks < 2; ks++)
      bv[e][ks] = *(const bf16x8*)&pT[e * 16 + (lane & 15)][ks * 32 + (lane >> 4) * 8];
  const f32x4 fzero = {0.0f, 0.0f, 0.0f, 0.0f};
  for (int it = 0; it < 4; it++) {
    const int rbase = it * 64 + wave * 16;
    const ushort* qrow = qb + (size_t)rbase * 64;
    const bf16x8 a0 = *(const bf16x8*)(qrow + (size_t)(lane & 15) * 64 + (lane >> 4) * 8);
    const bf16x8 a1 = *(const bf16x8*)(qrow + (size_t)(lane & 15) * 64 + (lane >> 4) * 8 + 32);
    f32x4 acc[4];
#pragma unroll
    for (int e = 0; e < 4; e++) acc[e] = fzero;
#pragma unroll
    for (int e = 0; e < 4; e++) {
      acc[e] = __builtin_amdgcn_mfma_f32_16x16x32_bf16(a0, bv[e][0], acc[e], 0, 0, 0);
      acc[e] = __builtin_amdgcn_mfma_f32_16x16x32_bf16(a1, bv[e][1], acc[e], 0, 0, 0);
    }
#pragma unroll
    for (int e = 0; e < 4; e++)
#pragma unroll
      for (int r = 0; r < 4; r++)
        ob[(size_t)(rbase + (lane >> 4) * 4 + r) * 64 + e * 16 + (lane & 15)] = acc[e][r];
  }
}

extern "C" void kernel_launch(void* const* d_in, const int* in_sizes, int n_in,
                              void* d_out, int out_size, void* d_ws, size_t ws_size,
                              hipStream_t stream) {
  const float* q_in = (const float*)d_in[0];
  const float* k_in = (const float*)d_in[1];
  const float* v_in = (const float*)d_in[2];
  const float* Wq = (const float*)d_in[3];
  const float* Wk = (const float*)d_in[4];
  const float* Wv = (const float*)d_in[5];
  const float* ksc = (const float*)d_in[6];
  const float* kbi = (const float*)d_in[7];
  const float* vsc = (const float*)d_in[8];
  const float* vbi = (const float*)d_in[9];

  float* att = (float*)d_out;                    // 33554432 fp32
  float* pout = att + (size_t)PROJ_ELEMS;        // 262144 fp32

  // new layout: a_bf (3x64MB) | q/k/v proj bf16 (3x64MB) | Wt bf16 (6MB) | praw2 (16MB)
  const size_t need_new = (size_t)3 * PROJ_ELEMS * 2 * 2   // a_bf + proj
                        + (size_t)3 * 1024 * 1024 * 2      // Wt
                        + (size_t)16 * 262144 * 4;         // praw2 partials
  if (ws_size >= need_new) {
    ushort* a_bf = (ushort*)d_ws;
    ushort* q_proj = a_bf + (size_t)3 * PROJ_ELEMS;
    ushort* k_proj = q_proj + (size_t)PROJ_ELEMS;
    ushort* v_proj = k_proj + (size_t)PROJ_ELEMS;
    ushort* wtb = v_proj + (size_t)PROJ_ELEMS;
    float* praw2 = (float*)(wtb + (size_t)3 * 1024 * 1024);

    wt_kernel<<<768, 256, 0, stream>>>(Wq, Wk, Wv, wtb);
    cast_kernel<<<6144, 256, 0, stream>>>(q_in, k_in, v_in, a_bf);
    gemm_qkv_kernel<<<6144, 256, 0, stream>>>(a_bf, wtb, q_proj, ksc, kbi, vsc, vbi);
    pattn_kernel<<<1024, 256, 0, stream>>>(k_proj, v_proj, praw2);
    preduce_kernel<<<1024, 256, 0, stream>>>(praw2, pout);
    outgemm_kernel<<<2048, 256, 0, stream>>>(q_proj, pout, att);
  } else {
    // legacy layout: proj (3x64MB) | Wt | praw2
    ushort* q_proj = (ushort*)d_ws;
    ushort* k_proj = q_proj + (size_t)PROJ_ELEMS;
    ushort* v_proj = k_proj + (size_t)PROJ_ELEMS;
    ushort* wtb = v_proj + (size_t)PROJ_ELEMS;
    float* praw2 = (float*)(wtb + (size_t)3 * 1024 * 1024);

    wt_kernel<<<768, 256, 0, stream>>>(Wq, Wk, Wv, wtb);
    gemm_qkv_legacy<<<6144, 256, 0, stream>>>(q_in, k_in, v_in, wtb, q_proj,
                                              ksc, kbi, vsc, vbi);
    pattn_kernel<<<1024, 256, 0, stream>>>(k_proj, v_proj, praw2);
    preduce_kernel<<<1024, 256, 0, stream>>>(praw2, pout);
    outgemm_kernel<<<2048, 256, 0, stream>>>(q_proj, pout, att);
  }
}